// Round 9
// baseline (189.297 us; speedup 1.0000x reference)
//
#include <hip/hip_runtime.h>

typedef _Float16 h8 __attribute__((ext_vector_type(8)));
typedef _Float16 h4 __attribute__((ext_vector_type(4)));
typedef float f32x4 __attribute__((ext_vector_type(4)));

union HU { _Float16 h; unsigned short u; };
__device__ __forceinline__ unsigned short f2h(float f) { HU x; x.h = (_Float16)f; return x.u; }
__device__ __forceinline__ float h2f(unsigned short u) { HU x; x.u = u; return (float)x.h; }

#define MFMA16(a, b, c) __builtin_amdgcn_mfma_f32_16x16x32_f16((a), (b), (c), 0, 0, 0)

// ---------------------------------------------------------------------------
// k_prep (grid-stride, 256 blocks): pack all MFMA B-fragments.
// 16x16x32 B-frag: lane holds B[k=(lane>>4)*8+j][n=lane&15].
// Big loops (w1hd, w2hd) are SOURCE-indexed for coalesced loads: thread walks
// consecutive n for fixed k (contiguous fp32 reads), computes the frag slot
//   e = ((kk*NT + nt)*64 + ((k&31)>>3)*16 + (n&15))*8 + (k&7)
// which exactly inverts the old destination-indexed mapping.
// ---------------------------------------------------------------------------
__global__ void k_prep(const float* __restrict__ w1, const float* __restrict__ w2,
                       const float* __restrict__ w3,
                       const float* __restrict__ ptw1, const float* __restrict__ cfw1,
                       const float* __restrict__ ptw2, const float* __restrict__ ptw3,
                       const float* __restrict__ cfw2,
                       unsigned short* __restrict__ w1f,
                       unsigned short* __restrict__ w2f,
                       unsigned short* __restrict__ w3f,
                       unsigned short* __restrict__ w1hd,
                       unsigned short* __restrict__ w2hd,
                       unsigned short* __restrict__ w3hd) {
    int gid = blockIdx.x * 256 + threadIdx.x;
    int gs = gridDim.x * 256;
    for (int e = gid; e < 512; e += gs) {
        int j = e & 7, lane = e >> 3;
        int k = ((lane >> 4) * 8) + j, oc = lane & 15;
        float v = 0.f;
        if (k < 27) { int t = k / 3, ic = k % 3; v = w1[oc * 27 + ic * 9 + t]; }
        w1f[e] = f2h(v);
    }
    for (int e = gid; e < 9216; e += gs) {
        int j = e & 7, lane = (e >> 3) & 63, fo = e >> 9;   // fo = t*2+ot
        int ot = fo & 1, t = fo >> 1;
        int k = ((lane >> 4) * 8) + j, oc = ot * 16 + (lane & 15);
        float v = (k < 16) ? w2[oc * 144 + k * 9 + t] : 0.f;
        w2f[e] = f2h(v);
    }
    for (int e = gid; e < 18432; e += gs) {
        int j = e & 7, lane = (e >> 3) & 63, fo = e >> 9;   // fo = (otp*9+t)*2+oti
        int oti = fo & 1, t = (fo >> 1) % 9, otp = (fo >> 1) / 9;
        int ic = ((lane >> 4) * 8) + j, oc = (otp * 2 + oti) * 16 + (lane & 15);
        w3f[e] = f2h(w3[oc * 288 + ic * 9 + t]);
    }
    // w1hd: source-indexed over (k,n) in [0,608) x [0,192)
    for (int s = gid; s < 608 * 192; s += gs) {
        int k = s / 192, n = s - k * 192;
        float v = 0.f;
        if (k < 584) v = (n < 128) ? ptw1[k * 128 + n] : cfw1[k * 64 + (n - 128)];
        int kk = k >> 5, hi = (k & 31) >> 3, j = k & 7, nt = n >> 4;
        int e = (((kk * 12 + nt) << 6) | (hi << 4) | (n & 15)) << 3 | j;
        w1hd[e] = f2h(v);
    }
    // w2hd: source-indexed over (k,n) in [0,128) x [0,64)
    for (int s = gid; s < 8192; s += gs) {
        int k = s >> 6, n = s & 63;
        float v = ptw2[k * 64 + n];
        int kk = k >> 5, hi = (k & 31) >> 3, j = k & 7, nt = n >> 4;
        int e = ((((kk << 2) | nt) << 6) | (hi << 4) | (n & 15)) << 3 | j;
        w2hd[e] = f2h(v);
    }
    for (int e = gid; e < 2048; e += gs) {
        int j = e & 7, lane = (e >> 3) & 63, kk = e >> 9;
        int k = kk * 32 + ((lane >> 4) * 8) + j, n = lane & 15;
        float v = 0.f;
        if (k < 64) { if (n < 2) v = ptw3[k * 2 + n]; }
        else        { if (n == 2) v = cfw2[k - 64]; }
        w3hd[e] = f2h(v);
    }
}

// ---------------------------------------------------------------------------
// k_fused: UNCHANGED from round 8 (101.8 us measured). conv1->conv2->pool->
// conv3 (+quantum) AND both MLP heads; feats never touches HBM.
// ---------------------------------------------------------------------------
#define BDS 194
#define A1S 584
#define A2S 296
#define FTS 616
#define HSH 200
#define RA_OFF 19712
#define O_OFF 26112
#define LDSTOT 26368

template<int PP0, int PP1>
__device__ __forceinline__ void conv2_compute(
    const unsigned short* A1, const h8* W2r, float b2v0, float b2v1,
    int sA1, int q, float pooled[5][2][4])
{
    #pragma unroll
    for (int pi = 0; pi < PP1 - PP0; pi++) {
        const int pp = PP0 + pi;
        #pragma unroll
        for (int sub = 0; sub < 4; sub++) {
            const int y = (pp / 3) * 2 + (sub >> 1), x = (pp % 3) * 2 + (sub & 1);
            f32x4 acc0 = {0.f, 0.f, 0.f, 0.f}, acc1 = {0.f, 0.f, 0.f, 0.f};
            #pragma unroll
            for (int t = 0; t < 9; t++) {
                const int sy = y + t / 3 - 1, sx = x + t % 3 - 1;
                if (sy < 0 || sy >= 6 || sx < 0 || sx >= 6) continue;
                h8 a = *(const h8*)&A1[sA1 + (sy * 6 + sx) * 16 + (q & 1) * 8];
                acc0 = MFMA16(a, W2r[t * 2 + 0], acc0);
                acc1 = MFMA16(a, W2r[t * 2 + 1], acc1);
            }
            #pragma unroll
            for (int r = 0; r < 4; r++) {
                pooled[pi][0][r] = fmaxf(pooled[pi][0][r], acc0[r] + b2v0);
                pooled[pi][1][r] = fmaxf(pooled[pi][1][r], acc1[r] + b2v1);
            }
        }
    }
}

template<int PP0, int PP1>
__device__ __forceinline__ void conv2_store(
    unsigned short* A2, const float pooled[5][2][4], int q, int col)
{
    #pragma unroll
    for (int pi = 0; pi < PP1 - PP0; pi++)
        #pragma unroll
        for (int ot = 0; ot < 2; ot++)
            #pragma unroll
            for (int r = 0; r < 4; r++)
                A2[(q * 4 + r) * A2S + (PP0 + pi) * 32 + ot * 16 + col] =
                    f2h(pooled[pi][ot][r]);
}

__global__ __launch_bounds__(256, 3) void k_fused(
    const float* __restrict__ board,
    const float* __restrict__ b1, const float* __restrict__ b2,
    const float* __restrict__ b3, const float* __restrict__ qp,
    const unsigned short* __restrict__ w1f,
    const unsigned short* __restrict__ w2f,
    const unsigned short* __restrict__ w3f,
    const unsigned short* __restrict__ w1hd,
    const unsigned short* __restrict__ w2hd,
    const unsigned short* __restrict__ w3hd,
    const float* __restrict__ ptb1, const float* __restrict__ ptb2,
    const float* __restrict__ ptb3, const float* __restrict__ cfb1,
    const float* __restrict__ cfb2,
    float* __restrict__ out)
{
    __shared__ __align__(16) unsigned short LDSH[LDSTOT];
    const int tid = threadIdx.x, wid = tid >> 6, lane = tid & 63;
    const int g = wid >> 1, w2 = wid & 1;
    const int col = lane & 15, q = lane >> 4;
    const long long gg0 = (long long)blockIdx.x * 32;
    const f32x4 ZERO4 = {0.f, 0.f, 0.f, 0.f};

    unsigned short* A1 = LDSH + g * 9856;
    unsigned short* A2 = A1;                          // overlay (barriered)
    unsigned short* Hb = LDSH + RA_OFF;               // overlays BD (dead)
    float* O = (float*)(LDSH + O_OFF);

    // ---- 1. zero BD region + A1 tail cols 576..583 (NaN-proofing) ----
    for (int e = tid; e < 1552; e += 256)
        ((unsigned long long*)LDSH)[4928 + e] = 0ULL;   // hw 19712..25920
    {
        int g2 = tid >> 7, r = (tid >> 3) & 15, z = tid & 7;
        LDSH[g2 * 9856 + r * A1S + 576 + z] = 0;
    }
    __syncthreads();

    // ---- 2. stage board fp32 -> fp16, pos-padded 8x8, ch-last ----
    for (int e = tid; e < 32 * 108; e += 256) {
        int ss = e / 108, r2 = e % 108, ch = r2 / 36, p = r2 % 36;
        float v = board[gg0 * 108 + e];
        LDSH[RA_OFF + (ss >> 4) * 3104 + (ss & 15) * BDS +
             ((p / 6 + 1) * 8 + (p % 6) + 1) * 3 + ch] = f2h(v);
    }
    __syncthreads();

    // ---- 3. quantum -> register (written into FT later) ----
    float qv;
    {
        int ss = tid >> 3, qq = tid & 7;
        int base = RA_OFF + (ss >> 4) * 3104 + (ss & 15) * BDS;
        int p8a = ((qq / 6 + 1) * 8 + (qq % 6) + 1) * 3;
        int e2 = (qq + 1) & 7;
        int p8b = ((e2 / 6 + 1) * 8 + (e2 % 6) + 1) * 3;
        float xq = h2f(LDSH[base + p8a]);
        float xn = h2f(LDSH[base + p8b]);
        float st = 0.f;
        for (int l = 0; l < 3; l++) {
            float a0 = qp[l * 24 + qq * 3], a1 = qp[l * 24 + qq * 3 + 1],
                  a2 = qp[l * 24 + qq * 3 + 2];
            st = sinf(a0 * xq) * cosf(a1 * xn) + tanhf(a2 * st);
        }
        qv = st;
    }

    // ---- 4. conv1: group g, position half w2 ----
    {
        int dlt[8];
        #pragma unroll
        for (int j = 0; j < 8; j++) {
            int k = q * 8 + j;
            if (k < 27) { int t = k / 3, c = k % 3;
                          dlt[j] = ((t / 3 - 1) * 8 + (t % 3 - 1)) * 3 + c; }
            else dlt[j] = 0;
        }
        h8 w1r = ((const h8*)w1f)[lane];
        float b1v = b1[col];
        const int sB = RA_OFF + g * 3104 + col * BDS;
        for (int p = w2 * 18; p < w2 * 18 + 18; p++) {
            int ab = sB + ((p / 6 + 1) * 8 + (p % 6) + 1) * 3;
            union { h8 v; _Float16 e[8]; } af;
            #pragma unroll
            for (int j = 0; j < 8; j++) { HU z; z.u = LDSH[ab + dlt[j]]; af.e[j] = z.h; }
            f32x4 c = MFMA16(af.v, w1r, ZERO4);
            #pragma unroll
            for (int r = 0; r < 4; r++)
                A1[(q * 4 + r) * A1S + p * 16 + col] = f2h(fmaxf(c[r] + b1v, 0.f));
        }
    }
    __syncthreads();

    // ---- 5. conv2 (+relu+pool), pooled cells 5/4 across the group's waves ----
    float pooled[5][2][4];
    #pragma unroll
    for (int pi = 0; pi < 5; pi++)
        #pragma unroll
        for (int ot = 0; ot < 2; ot++)
            #pragma unroll
            for (int r = 0; r < 4; r++) pooled[pi][ot][r] = 0.f;
    {
        h8 W2r[18];
        #pragma unroll
        for (int f = 0; f < 18; f++) W2r[f] = ((const h8*)w2f)[f * 64 + lane];
        float b2v0 = b2[col], b2v1 = b2[16 + col];
        const int sA1 = col * A1S;
        if (w2 == 0) conv2_compute<0, 5>(A1, W2r, b2v0, b2v1, sA1, q, pooled);
        else         conv2_compute<5, 9>(A1, W2r, b2v0, b2v1, sA1, q, pooled);
    }
    __syncthreads();
    if (w2 == 0) conv2_store<0, 5>(A2, pooled, q, col);
    else         conv2_store<5, 9>(A2, pooled, q, col);
    __syncthreads();

    // ---- 6. conv3 -> registers (otp = w2) ----
    f32x4 c3a[9], c3b[9];
    {
        const int otp = w2;
        const int sA2 = col * A2S;
        h8 W3r[18];
        #pragma unroll
        for (int f = 0; f < 18; f++)
            W3r[f] = ((const h8*)w3f)[(otp * 18 + f) * 64 + lane];
        #pragma unroll
        for (int p = 0; p < 9; p++) {
            const int y = p / 3, x = p % 3;
            f32x4 acc0 = ZERO4, acc1 = ZERO4;
            #pragma unroll
            for (int t = 0; t < 9; t++) {
                const int sy = y + t / 3 - 1, sx = x + t % 3 - 1;
                if (sy < 0 || sy >= 3 || sx < 0 || sx >= 3) continue;
                h8 a = *(const h8*)&A2[sA2 + (sy * 3 + sx) * 32 + q * 8];
                acc0 = MFMA16(a, W3r[t * 2 + 0], acc0);
                acc1 = MFMA16(a, W3r[t * 2 + 1], acc1);
            }
            c3a[p] = acc0; c3b[p] = acc1;
        }
    }
    __syncthreads();   // all A2 reads done before FT overlays region B

    // ---- 7. write FT (feats tile) + quantum + zero tail cols 584..615 ----
    {
        const int otp = w2;
        float b3v0 = b3[(otp * 2 + 0) * 16 + col];
        float b3v1 = b3[(otp * 2 + 1) * 16 + col];
        int oc0 = (otp * 2 + 0) * 16 + col, oc1 = (otp * 2 + 1) * 16 + col;
        #pragma unroll
        for (int p = 0; p < 9; p++)
            #pragma unroll
            for (int r = 0; r < 4; r++) {
                int row = g * 16 + q * 4 + r;
                LDSH[row * FTS + oc0 * 9 + p] = f2h(fmaxf(c3a[p][r] + b3v0, 0.f));
                LDSH[row * FTS + oc1 * 9 + p] = f2h(fmaxf(c3b[p][r] + b3v1, 0.f));
            }
        LDSH[(tid >> 3) * FTS + 576 + (tid & 7)] = f2h(qv);
        for (int e = tid; e < 1024; e += 256)
            LDSH[(e >> 5) * FTS + 584 + (e & 31)] = 0;
    }
    __syncthreads();

    // ---- 8. heads L1: K=608 (19 kk), wave does nt-tiles wid*3..+2, both mt ----
    {
        f32x4 acc[2][3];
        #pragma unroll
        for (int mt = 0; mt < 2; mt++)
            #pragma unroll
            for (int nt = 0; nt < 3; nt++) acc[mt][nt] = ZERO4;
        const h8* wp1 = (const h8*)w1hd;
        const int ntb = wid * 3;
        for (int kk = 0; kk < 19; kk++) {
            h8 a0 = *(const h8*)&LDSH[col * FTS + kk * 32 + q * 8];
            h8 a1 = *(const h8*)&LDSH[(16 + col) * FTS + kk * 32 + q * 8];
            h8 b[3];
            #pragma unroll
            for (int nt = 0; nt < 3; nt++)
                b[nt] = wp1[(kk * 12 + ntb + nt) * 64 + lane];
            #pragma unroll
            for (int nt = 0; nt < 3; nt++) {
                acc[0][nt] = MFMA16(a0, b[nt], acc[0][nt]);
                acc[1][nt] = MFMA16(a1, b[nt], acc[1][nt]);
            }
        }
        #pragma unroll
        for (int nt = 0; nt < 3; nt++) {
            int ntg = ntb + nt;
            float bv = (ntg < 8) ? ptb1[ntg * 16 + col] : cfb1[(ntg - 8) * 16 + col];
            #pragma unroll
            for (int mt = 0; mt < 2; mt++)
                #pragma unroll
                for (int r = 0; r < 4; r++)
                    Hb[(mt * 16 + q * 4 + r) * HSH + ntg * 16 + col] =
                        f2h(fmaxf(acc[mt][nt][r] + bv, 0.f));
        }
    }
    __syncthreads();

    // ---- 9. heads L2: nt = wid, both mt; read cols 0..127, write cols 0..63 ----
    {
        f32x4 acc2[2];
        acc2[0] = ZERO4; acc2[1] = ZERO4;
        const h8* wp2 = (const h8*)w2hd;
        const int nt2 = wid;
        #pragma unroll
        for (int kk = 0; kk < 4; kk++) {
            h8 a0 = *(const h8*)&Hb[col * HSH + kk * 32 + q * 8];
            h8 a1 = *(const h8*)&Hb[(16 + col) * HSH + kk * 32 + q * 8];
            h8 b = wp2[(kk * 4 + nt2) * 64 + lane];
            acc2[0] = MFMA16(a0, b, acc2[0]);
            acc2[1] = MFMA16(a1, b, acc2[1]);
        }
        __syncthreads();   // all L2 reads done before overwriting cols 0..63
        float bv2 = ptb2[nt2 * 16 + col];
        #pragma unroll
        for (int mt = 0; mt < 2; mt++)
            #pragma unroll
            for (int r = 0; r < 4; r++)
                Hb[(mt * 16 + q * 4 + r) * HSH + nt2 * 16 + col] =
                    f2h(fmaxf(acc2[mt][r] + bv2, 0.f));
    }
    __syncthreads();

    // ---- 10. heads L3 + epilogue: waves 0,1 handle mt = wid ----
    if (wid < 2) {
        const int mt = wid;
        f32x4 a3 = ZERO4;
        #pragma unroll
        for (int kk = 0; kk < 4; kk++) {
            int base = (kk < 2) ? kk * 32 : kk * 32 + 64;
            h8 a = *(const h8*)&Hb[(mt * 16 + col) * HSH + base + q * 8];
            h8 b = ((const h8*)w3hd)[kk * 64 + lane];
            a3 = MFMA16(a, b, a3);
        }
        if (col < 3) {
            float bv = (col < 2) ? ptb3[col] : cfb2[0];
            #pragma unroll
            for (int r = 0; r < 4; r++)
                O[(mt * 16 + q * 4 + r) * 4 + col] = a3[r] + bv;
        }
        if (lane < 16) {
            int s = mt * 16 + lane;
            float l0 = O[s * 4 + 0], l1 = O[s * 4 + 1], l2 = O[s * 4 + 2];
            float m = fmaxf(l0, l1);
            float e0 = expf(l0 - m), e1 = expf(l1 - m);
            float inv = 1.f / (e0 + e1);
            float* op = out + (gg0 + s) * 3;
            op[0] = e0 * inv;
            op[1] = e1 * inv;
            op[2] = 1.f / (1.f + expf(-l2));
        }
    }
}

extern "C" void kernel_launch(void* const* d_in, const int* in_sizes, int n_in,
                              void* d_out, int out_size, void* d_ws, size_t ws_size,
                              hipStream_t stream) {
    const float* board = (const float*)d_in[0];
    const float* c1w  = (const float*)d_in[2];
    const float* c1b  = (const float*)d_in[3];
    const float* c2w  = (const float*)d_in[4];
    const float* c2b  = (const float*)d_in[5];
    const float* c3w  = (const float*)d_in[6];
    const float* c3b  = (const float*)d_in[7];
    const float* qp   = (const float*)d_in[8];
    const float* ptw1 = (const float*)d_in[9];
    const float* ptb1 = (const float*)d_in[10];
    const float* ptw2 = (const float*)d_in[11];
    const float* ptb2 = (const float*)d_in[12];
    const float* ptw3 = (const float*)d_in[13];
    const float* ptb3 = (const float*)d_in[14];
    const float* cfw1 = (const float*)d_in[15];
    const float* cfb1 = (const float*)d_in[16];
    const float* cfw2 = (const float*)d_in[17];
    const float* cfb2 = (const float*)d_in[18];
    float* out = (float*)d_out;

    int Btot = in_sizes[0] / 108;          // 65536

    // ws layout (bytes): w1f@0(1K) w2f@1024(18K) w3f@19456(36K) w1hd@56320(228K)
    //                    w2hd@289792(16K) w3hd@306176(4K). No feats array.
    unsigned short* w1f   = (unsigned short*)d_ws;
    unsigned short* w2f   = (unsigned short*)((char*)d_ws + 1024);
    unsigned short* w3f   = (unsigned short*)((char*)d_ws + 19456);
    unsigned short* w1hd  = (unsigned short*)((char*)d_ws + 56320);
    unsigned short* w2hd  = (unsigned short*)((char*)d_ws + 289792);
    unsigned short* w3hd  = (unsigned short*)((char*)d_ws + 306176);

    hipLaunchKernelGGL(k_prep, dim3(256), dim3(256), 0, stream,
                       c1w, c2w, c3w, ptw1, cfw1, ptw2, ptw3, cfw2,
                       w1f, w2f, w3f, w1hd, w2hd, w3hd);
    hipLaunchKernelGGL(k_fused, dim3(Btot / 32), dim3(256), 0, stream,
                       board, c1b, c2b, c3b, qp, w1f, w2f, w3f,
                       w1hd, w2hd, w3hd, ptb1, ptb2, ptb3, cfb1, cfb2, out);
}

// Round 10
// 181.301 us; speedup vs baseline: 1.0441x; 1.0441x over previous
//
#include <hip/hip_runtime.h>

typedef _Float16 h8 __attribute__((ext_vector_type(8)));
typedef _Float16 h4 __attribute__((ext_vector_type(4)));
typedef float f32x4 __attribute__((ext_vector_type(4)));

union HU { _Float16 h; unsigned short u; };
__device__ __forceinline__ unsigned short f2h(float f) { HU x; x.h = (_Float16)f; return x.u; }
__device__ __forceinline__ float h2f(unsigned short u) { HU x; x.u = u; return (float)x.h; }

#define MFMA16(a, b, c) __builtin_amdgcn_mfma_f32_16x16x32_f16((a), (b), (c), 0, 0, 0)

// ---------------------------------------------------------------------------
// k_prep (grid-stride, 256 blocks): pack all MFMA B-fragments.
// 16x16x32 B-frag: lane holds B[k=(lane>>4)*8+j][n=lane&15].
//  w1f [f2][lane][8]: conv1 ch4 two-fragment layout (r7-validated):
//    f=0: k -> window row r=k>>4 (0,1), within=k&15; f=1: r=2, within=k;
//    tx=within>>2 (dx 0..3, 3 valid), ch=within&3 (3 valid); n=oc.
//  w1hd k-map: FT feature order is [p][oc]: k<576 -> f=(k&63)*9+(k>>6);
//    576..583 -> quantum row k; >=584 -> 0.
// ---------------------------------------------------------------------------
__global__ void k_prep(const float* __restrict__ w1, const float* __restrict__ w2,
                       const float* __restrict__ w3,
                       const float* __restrict__ ptw1, const float* __restrict__ cfw1,
                       const float* __restrict__ ptw2, const float* __restrict__ ptw3,
                       const float* __restrict__ cfw2,
                       unsigned short* __restrict__ w1f,
                       unsigned short* __restrict__ w2f,
                       unsigned short* __restrict__ w3f,
                       unsigned short* __restrict__ w1hd,
                       unsigned short* __restrict__ w2hd,
                       unsigned short* __restrict__ w3hd) {
    int gid = blockIdx.x * 256 + threadIdx.x;
    int gs = gridDim.x * 256;
    for (int e = gid; e < 1024; e += gs) {
        int f = e >> 9, lane = (e >> 3) & 63, j = e & 7;
        int k = ((lane >> 4) << 3) + j, oc = lane & 15;
        int r, within;
        if (f == 0) { r = k >> 4; within = k & 15; }
        else        { r = 2;      within = k; }
        int tx = within >> 2, ch = within & 3;
        float v = 0.f;
        if (tx < 3 && ch < 3) v = w1[oc * 27 + ch * 9 + r * 3 + tx];
        w1f[e] = f2h(v);
    }
    for (int e = gid; e < 9216; e += gs) {
        int j = e & 7, lane = (e >> 3) & 63, fo = e >> 9;   // fo = t*2+ot
        int ot = fo & 1, t = fo >> 1;
        int k = ((lane >> 4) * 8) + j, oc = ot * 16 + (lane & 15);
        float v = (k < 16) ? w2[oc * 144 + k * 9 + t] : 0.f;
        w2f[e] = f2h(v);
    }
    for (int e = gid; e < 18432; e += gs) {
        int j = e & 7, lane = (e >> 3) & 63, fo = e >> 9;   // fo = (otp*9+t)*2+oti
        int oti = fo & 1, t = (fo >> 1) % 9, otp = (fo >> 1) / 9;
        int ic = ((lane >> 4) * 8) + j, oc = (otp * 2 + oti) * 16 + (lane & 15);
        w3f[e] = f2h(w3[oc * 288 + ic * 9 + t]);
    }
    // w1hd: source-indexed over (k,n); k-order matches FT [p][oc] layout
    for (int s = gid; s < 608 * 192; s += gs) {
        int k = s / 192, n = s - k * 192;
        float v = 0.f;
        if (k < 584) {
            int f = (k < 576) ? ((k & 63) * 9 + (k >> 6)) : k;
            v = (n < 128) ? ptw1[f * 128 + n] : cfw1[f * 64 + (n - 128)];
        }
        int kk = k >> 5, hi = (k & 31) >> 3, j = k & 7, nt = n >> 4;
        int e = (((kk * 12 + nt) << 6) | (hi << 4) | (n & 15)) << 3 | j;
        w1hd[e] = f2h(v);
    }
    for (int s = gid; s < 8192; s += gs) {
        int k = s >> 6, n = s & 63;
        float v = ptw2[k * 64 + n];
        int kk = k >> 5, hi = (k & 31) >> 3, j = k & 7, nt = n >> 4;
        int e = ((((kk << 2) | nt) << 6) | (hi << 4) | (n & 15)) << 3 | j;
        w2hd[e] = f2h(v);
    }
    for (int e = gid; e < 2048; e += gs) {
        int j = e & 7, lane = (e >> 3) & 63, kk = e >> 9;
        int k = kk * 32 + ((lane >> 4) * 8) + j, n = lane & 15;
        float v = 0.f;
        if (k < 64) { if (n < 2) v = ptw3[k * 2 + n]; }
        else        { if (n == 2) v = cfw2[k - 64]; }
        w3hd[e] = f2h(v);
    }
}

// ---------------------------------------------------------------------------
// k_fused: convs + heads, one block = 32 samples (2 groups of 16), 4 waves.
// Conv1 uses ch-padded-4 board staged PER GROUP through one BD buffer
// (aligned ds_read_b64 A-fragments, r7-validated math). FT layout [p][oc].
// LDS (hw): region B @0: A1_g (stride 584 @g*9856) / A2_g overlay -> FT
//   (32 rows stride 616). region A @19712: BD (16 x 260 = 4160, per-group
//   staging) -> H (32 x 200 = 6400 overlays BD); O @26112. tot 26368 hw.
// ---------------------------------------------------------------------------
#define BDS4 260
#define BDH4 (16 * BDS4)
#define A1S 584
#define A2S 296
#define FTS 616
#define HSH 200
#define RA_OFF 19712
#define O_OFF 26112
#define LDSTOT 26368

template<int PP0, int PP1>
__device__ __forceinline__ void conv2_compute(
    const unsigned short* A1, const h8* W2r, float b2v0, float b2v1,
    int sA1, int q, float pooled[5][2][4])
{
    #pragma unroll
    for (int pi = 0; pi < PP1 - PP0; pi++) {
        const int pp = PP0 + pi;
        #pragma unroll
        for (int sub = 0; sub < 4; sub++) {
            const int y = (pp / 3) * 2 + (sub >> 1), x = (pp % 3) * 2 + (sub & 1);
            f32x4 acc0 = {0.f, 0.f, 0.f, 0.f}, acc1 = {0.f, 0.f, 0.f, 0.f};
            #pragma unroll
            for (int t = 0; t < 9; t++) {
                const int sy = y + t / 3 - 1, sx = x + t % 3 - 1;
                if (sy < 0 || sy >= 6 || sx < 0 || sx >= 6) continue;
                h8 a = *(const h8*)&A1[sA1 + (sy * 6 + sx) * 16 + (q & 1) * 8];
                acc0 = MFMA16(a, W2r[t * 2 + 0], acc0);
                acc1 = MFMA16(a, W2r[t * 2 + 1], acc1);
            }
            #pragma unroll
            for (int r = 0; r < 4; r++) {
                pooled[pi][0][r] = fmaxf(pooled[pi][0][r], acc0[r] + b2v0);
                pooled[pi][1][r] = fmaxf(pooled[pi][1][r], acc1[r] + b2v1);
            }
        }
    }
}

template<int PP0, int PP1>
__device__ __forceinline__ void conv2_store(
    unsigned short* A2, const float pooled[5][2][4], int q, int col)
{
    #pragma unroll
    for (int pi = 0; pi < PP1 - PP0; pi++)
        #pragma unroll
        for (int ot = 0; ot < 2; ot++)
            #pragma unroll
            for (int r = 0; r < 4; r++)
                A2[(q * 4 + r) * A2S + (PP0 + pi) * 32 + ot * 16 + col] =
                    f2h(pooled[pi][ot][r]);
}

__global__ __launch_bounds__(256, 3) void k_fused(
    const float* __restrict__ board,
    const float* __restrict__ b1, const float* __restrict__ b2,
    const float* __restrict__ b3, const float* __restrict__ qp,
    const unsigned short* __restrict__ w1f,
    const unsigned short* __restrict__ w2f,
    const unsigned short* __restrict__ w3f,
    const unsigned short* __restrict__ w1hd,
    const unsigned short* __restrict__ w2hd,
    const unsigned short* __restrict__ w3hd,
    const float* __restrict__ ptb1, const float* __restrict__ ptb2,
    const float* __restrict__ ptb3, const float* __restrict__ cfb1,
    const float* __restrict__ cfb2,
    float* __restrict__ out)
{
    __shared__ __align__(16) unsigned short LDSH[LDSTOT];
    const int tid = threadIdx.x, wid = tid >> 6, lane = tid & 63;
    const int g = wid >> 1, w2 = wid & 1;
    const int col = lane & 15, q = lane >> 4;
    const long long gg0 = (long long)blockIdx.x * 32;
    const f32x4 ZERO4 = {0.f, 0.f, 0.f, 0.f};

    unsigned short* A1 = LDSH + g * 9856;
    unsigned short* A2 = A1;                          // overlay (barriered)
    unsigned short* Hb = LDSH + RA_OFF;               // overlays BD (dead)
    float* O = (float*)(LDSH + O_OFF);

    // ---- 1. zero BD staging buffer ----
    for (int e = tid; e < BDH4 / 4; e += 256)
        ((unsigned long long*)(LDSH + RA_OFF))[e] = 0ULL;
    __syncthreads();

    // ---- 2. per-group: stage board (ch-pad-4) -> quantum + conv1 ----
    float qv[2];
    h8 w1r0 = ((const h8*)w1f)[lane];
    h8 w1r1 = ((const h8*)w1f)[64 + lane];
    float b1v = b1[col];
    #pragma unroll
    for (int gi = 0; gi < 2; gi++) {
        for (int e = tid; e < 16 * 108; e += 256) {
            int ss = e / 108, r2 = e % 108, ch = r2 / 36, p = r2 % 36;
            float v = board[(gg0 + gi * 16) * 108 + e];
            LDSH[RA_OFF + ss * BDS4 + ((p / 6 + 1) * 8 + (p % 6) + 1) * 4 + ch] =
                f2h(v);
        }
        __syncthreads();
        if (tid < 128) {
            int ss = tid >> 3, qq = tid & 7;
            int base = RA_OFF + ss * BDS4;
            int p8a = ((qq / 6 + 1) * 8 + (qq % 6) + 1) * 4;
            int e2 = (qq + 1) & 7;
            int p8b = ((e2 / 6 + 1) * 8 + (e2 % 6) + 1) * 4;
            float xq = h2f(LDSH[base + p8a]);
            float xn = h2f(LDSH[base + p8b]);
            float st = 0.f;
            for (int l = 0; l < 3; l++) {
                float a0 = qp[l * 24 + qq * 3], a1 = qp[l * 24 + qq * 3 + 1],
                      a2 = qp[l * 24 + qq * 3 + 2];
                st = sinf(a0 * xq) * cosf(a1 * xn) + tanhf(a2 * st);
            }
            qv[gi] = st;
        }
        // conv1: all 4 waves on this group, 9 positions each (aligned b64 A)
        {
            unsigned short* A1g = LDSH + gi * 9856;
            const int bs = RA_OFF + col * BDS4;
            const int rsel = q >> 1, wo = (q & 1) * 8;
            for (int p = wid * 9; p < wid * 9 + 9; p++) {
                int y = p / 6, x = p % 6;
                int ab1 = bs + ((y + rsel) * 8 + x) * 4 + wo;
                int ab2 = bs + ((y + 2) * 8 + x) * 4 + wo;
                union { h8 v; h4 h[2]; } a1v, a2v;
                a1v.h[0] = *(const h4*)&LDSH[ab1];
                a1v.h[1] = *(const h4*)&LDSH[ab1 + 4];
                a2v.h[0] = *(const h4*)&LDSH[ab2];
                a2v.h[1] = *(const h4*)&LDSH[ab2 + 4];
                f32x4 c = MFMA16(a1v.v, w1r0, ZERO4);
                c = MFMA16(a2v.v, w1r1, c);
                #pragma unroll
                for (int r = 0; r < 4; r++)
                    A1g[(q * 4 + r) * A1S + p * 16 + col] =
                        f2h(fmaxf(c[r] + b1v, 0.f));
            }
        }
        __syncthreads();   // BD reads done (restage for gi=1 / conv2 after)
    }

    // ---- 3. conv2 (+relu+pool), per group, cells 5/4 across its 2 waves ----
    float pooled[5][2][4];
    #pragma unroll
    for (int pi = 0; pi < 5; pi++)
        #pragma unroll
        for (int ot = 0; ot < 2; ot++)
            #pragma unroll
            for (int r = 0; r < 4; r++) pooled[pi][ot][r] = 0.f;
    {
        h8 W2r[18];
        #pragma unroll
        for (int f = 0; f < 18; f++) W2r[f] = ((const h8*)w2f)[f * 64 + lane];
        float b2v0 = b2[col], b2v1 = b2[16 + col];
        const int sA1 = col * A1S;
        if (w2 == 0) conv2_compute<0, 5>(A1, W2r, b2v0, b2v1, sA1, q, pooled);
        else         conv2_compute<5, 9>(A1, W2r, b2v0, b2v1, sA1, q, pooled);
    }
    __syncthreads();
    if (w2 == 0) conv2_store<0, 5>(A2, pooled, q, col);
    else         conv2_store<5, 9>(A2, pooled, q, col);
    __syncthreads();

    // ---- 4. conv3 -> registers (otp = w2) ----
    f32x4 c3a[9], c3b[9];
    {
        const int otp = w2;
        const int sA2 = col * A2S;
        h8 W3r[18];
        #pragma unroll
        for (int f = 0; f < 18; f++)
            W3r[f] = ((const h8*)w3f)[(otp * 18 + f) * 64 + lane];
        #pragma unroll
        for (int p = 0; p < 9; p++) {
            const int y = p / 3, x = p % 3;
            f32x4 acc0 = ZERO4, acc1 = ZERO4;
            #pragma unroll
            for (int t = 0; t < 9; t++) {
                const int sy = y + t / 3 - 1, sx = x + t % 3 - 1;
                if (sy < 0 || sy >= 3 || sx < 0 || sx >= 3) continue;
                h8 a = *(const h8*)&A2[sA2 + (sy * 3 + sx) * 32 + q * 8];
                acc0 = MFMA16(a, W3r[t * 2 + 0], acc0);
                acc1 = MFMA16(a, W3r[t * 2 + 1], acc1);
            }
            c3a[p] = acc0; c3b[p] = acc1;
        }
    }
    __syncthreads();   // all A2 reads done before FT overlays region B

    // ---- 5. write FT [p][oc] + quantum + zero tail cols 584..615 ----
    {
        const int otp = w2;
        float b3v0 = b3[(otp * 2 + 0) * 16 + col];
        float b3v1 = b3[(otp * 2 + 1) * 16 + col];
        int oc0 = (otp * 2 + 0) * 16 + col, oc1 = (otp * 2 + 1) * 16 + col;
        #pragma unroll
        for (int p = 0; p < 9; p++)
            #pragma unroll
            for (int r = 0; r < 4; r++) {
                int row = g * 16 + q * 4 + r;
                LDSH[row * FTS + p * 64 + oc0] = f2h(fmaxf(c3a[p][r] + b3v0, 0.f));
                LDSH[row * FTS + p * 64 + oc1] = f2h(fmaxf(c3b[p][r] + b3v1, 0.f));
            }
        if (tid < 128) {
            int ss = tid >> 3, qq = tid & 7;
            LDSH[ss * FTS + 576 + qq] = f2h(qv[0]);
            LDSH[(ss + 16) * FTS + 576 + qq] = f2h(qv[1]);
        }
        for (int e = tid; e < 1024; e += 256)
            LDSH[(e >> 5) * FTS + 584 + (e & 31)] = 0;
    }
    __syncthreads();

    // ---- 6. heads L1: K=608 (19 kk), wave does nt-tiles wid*3..+2, both mt ----
    {
        f32x4 acc[2][3];
        #pragma unroll
        for (int mt = 0; mt < 2; mt++)
            #pragma unroll
            for (int nt = 0; nt < 3; nt++) acc[mt][nt] = ZERO4;
        const h8* wp1 = (const h8*)w1hd;
        const int ntb = wid * 3;
        for (int kk = 0; kk < 19; kk++) {
            h8 a0 = *(const h8*)&LDSH[col * FTS + kk * 32 + q * 8];
            h8 a1 = *(const h8*)&LDSH[(16 + col) * FTS + kk * 32 + q * 8];
            h8 b[3];
            #pragma unroll
            for (int nt = 0; nt < 3; nt++)
                b[nt] = wp1[(kk * 12 + ntb + nt) * 64 + lane];
            #pragma unroll
            for (int nt = 0; nt < 3; nt++) {
                acc[0][nt] = MFMA16(a0, b[nt], acc[0][nt]);
                acc[1][nt] = MFMA16(a1, b[nt], acc[1][nt]);
            }
        }
        #pragma unroll
        for (int nt = 0; nt < 3; nt++) {
            int ntg = ntb + nt;
            float bv = (ntg < 8) ? ptb1[ntg * 16 + col] : cfb1[(ntg - 8) * 16 + col];
            #pragma unroll
            for (int mt = 0; mt < 2; mt++)
                #pragma unroll
                for (int r = 0; r < 4; r++)
                    Hb[(mt * 16 + q * 4 + r) * HSH + ntg * 16 + col] =
                        f2h(fmaxf(acc[mt][nt][r] + bv, 0.f));
        }
    }
    __syncthreads();

    // ---- 7. heads L2: nt = wid, both mt ----
    {
        f32x4 acc2[2];
        acc2[0] = ZERO4; acc2[1] = ZERO4;
        const h8* wp2 = (const h8*)w2hd;
        const int nt2 = wid;
        #pragma unroll
        for (int kk = 0; kk < 4; kk++) {
            h8 a0 = *(const h8*)&Hb[col * HSH + kk * 32 + q * 8];
            h8 a1 = *(const h8*)&Hb[(16 + col) * HSH + kk * 32 + q * 8];
            h8 b = wp2[(kk * 4 + nt2) * 64 + lane];
            acc2[0] = MFMA16(a0, b, acc2[0]);
            acc2[1] = MFMA16(a1, b, acc2[1]);
        }
        __syncthreads();   // all L2 reads done before overwriting cols 0..63
        float bv2 = ptb2[nt2 * 16 + col];
        #pragma unroll
        for (int mt = 0; mt < 2; mt++)
            #pragma unroll
            for (int r = 0; r < 4; r++)
                Hb[(mt * 16 + q * 4 + r) * HSH + nt2 * 16 + col] =
                    f2h(fmaxf(acc2[mt][r] + bv2, 0.f));
    }
    __syncthreads();

    // ---- 8. heads L3 + epilogue: waves 0,1 handle mt = wid ----
    if (wid < 2) {
        const int mt = wid;
        f32x4 a3 = ZERO4;
        #pragma unroll
        for (int kk = 0; kk < 4; kk++) {
            int base = (kk < 2) ? kk * 32 : kk * 32 + 64;
            h8 a = *(const h8*)&Hb[(mt * 16 + col) * HSH + base + q * 8];
            h8 b = ((const h8*)w3hd)[kk * 64 + lane];
            a3 = MFMA16(a, b, a3);
        }
        if (col < 3) {
            float bv = (col < 2) ? ptb3[col] : cfb2[0];
            #pragma unroll
            for (int r = 0; r < 4; r++)
                O[(mt * 16 + q * 4 + r) * 4 + col] = a3[r] + bv;
        }
        if (lane < 16) {
            int s = mt * 16 + lane;
            float l0 = O[s * 4 + 0], l1 = O[s * 4 + 1], l2 = O[s * 4 + 2];
            float m = fmaxf(l0, l1);
            float e0 = expf(l0 - m), e1 = expf(l1 - m);
            float inv = 1.f / (e0 + e1);
            float* op = out + (gg0 + s) * 3;
            op[0] = e0 * inv;
            op[1] = e1 * inv;
            op[2] = 1.f / (1.f + expf(-l2));
        }
    }
}

extern "C" void kernel_launch(void* const* d_in, const int* in_sizes, int n_in,
                              void* d_out, int out_size, void* d_ws, size_t ws_size,
                              hipStream_t stream) {
    const float* board = (const float*)d_in[0];
    const float* c1w  = (const float*)d_in[2];
    const float* c1b  = (const float*)d_in[3];
    const float* c2w  = (const float*)d_in[4];
    const float* c2b  = (const float*)d_in[5];
    const float* c3w  = (const float*)d_in[6];
    const float* c3b  = (const float*)d_in[7];
    const float* qp   = (const float*)d_in[8];
    const float* ptw1 = (const float*)d_in[9];
    const float* ptb1 = (const float*)d_in[10];
    const float* ptw2 = (const float*)d_in[11];
    const float* ptb2 = (const float*)d_in[12];
    const float* ptw3 = (const float*)d_in[13];
    const float* ptb3 = (const float*)d_in[14];
    const float* cfw1 = (const float*)d_in[15];
    const float* cfb1 = (const float*)d_in[16];
    const float* cfw2 = (const float*)d_in[17];
    const float* cfb2 = (const float*)d_in[18];
    float* out = (float*)d_out;

    int Btot = in_sizes[0] / 108;          // 65536

    // ws layout (bytes): w1f@0(2K) w2f@2048(18K) w3f@20480(36K) w1hd@57344(228K)
    //                    w2hd@290816(16K) w3hd@307200(4K)
    unsigned short* w1f   = (unsigned short*)d_ws;
    unsigned short* w2f   = (unsigned short*)((char*)d_ws + 2048);
    unsigned short* w3f   = (unsigned short*)((char*)d_ws + 20480);
    unsigned short* w1hd  = (unsigned short*)((char*)d_ws + 57344);
    unsigned short* w2hd  = (unsigned short*)((char*)d_ws + 290816);
    unsigned short* w3hd  = (unsigned short*)((char*)d_ws + 307200);

    hipLaunchKernelGGL(k_prep, dim3(256), dim3(256), 0, stream,
                       c1w, c2w, c3w, ptw1, cfw1, ptw2, ptw3, cfw2,
                       w1f, w2f, w3f, w1hd, w2hd, w3hd);
    hipLaunchKernelGGL(k_fused, dim3(Btot / 32), dim3(256), 0, stream,
                       board, c1b, c2b, c3b, qp, w1f, w2f, w3f,
                       w1hd, w2hd, w3hd, ptb1, ptb2, ptb3, cfb1, cfb2, out);
}

// Round 11
// 174.293 us; speedup vs baseline: 1.0861x; 1.0402x over previous
//
#include <hip/hip_runtime.h>

typedef _Float16 h8 __attribute__((ext_vector_type(8)));
typedef _Float16 h4 __attribute__((ext_vector_type(4)));
typedef float f32x4 __attribute__((ext_vector_type(4)));

union HU { _Float16 h; unsigned short u; };
__device__ __forceinline__ unsigned short f2h(float f) { HU x; x.h = (_Float16)f; return x.u; }
__device__ __forceinline__ float h2f(unsigned short u) { HU x; x.u = u; return (float)x.h; }

#define MFMA16(a, b, c) __builtin_amdgcn_mfma_f32_16x16x32_f16((a), (b), (c), 0, 0, 0)

// ---------------------------------------------------------------------------
// k_prep: UNCHANGED from round 10 (validated).
// ---------------------------------------------------------------------------
__global__ void k_prep(const float* __restrict__ w1, const float* __restrict__ w2,
                       const float* __restrict__ w3,
                       const float* __restrict__ ptw1, const float* __restrict__ cfw1,
                       const float* __restrict__ ptw2, const float* __restrict__ ptw3,
                       const float* __restrict__ cfw2,
                       unsigned short* __restrict__ w1f,
                       unsigned short* __restrict__ w2f,
                       unsigned short* __restrict__ w3f,
                       unsigned short* __restrict__ w1hd,
                       unsigned short* __restrict__ w2hd,
                       unsigned short* __restrict__ w3hd) {
    int gid = blockIdx.x * 256 + threadIdx.x;
    int gs = gridDim.x * 256;
    for (int e = gid; e < 1024; e += gs) {
        int f = e >> 9, lane = (e >> 3) & 63, j = e & 7;
        int k = ((lane >> 4) << 3) + j, oc = lane & 15;
        int r, within;
        if (f == 0) { r = k >> 4; within = k & 15; }
        else        { r = 2;      within = k; }
        int tx = within >> 2, ch = within & 3;
        float v = 0.f;
        if (tx < 3 && ch < 3) v = w1[oc * 27 + ch * 9 + r * 3 + tx];
        w1f[e] = f2h(v);
    }
    for (int e = gid; e < 9216; e += gs) {
        int j = e & 7, lane = (e >> 3) & 63, fo = e >> 9;   // fo = t*2+ot
        int ot = fo & 1, t = fo >> 1;
        int k = ((lane >> 4) * 8) + j, oc = ot * 16 + (lane & 15);
        float v = (k < 16) ? w2[oc * 144 + k * 9 + t] : 0.f;
        w2f[e] = f2h(v);
    }
    for (int e = gid; e < 18432; e += gs) {
        int j = e & 7, lane = (e >> 3) & 63, fo = e >> 9;   // fo = (otp*9+t)*2+oti
        int oti = fo & 1, t = (fo >> 1) % 9, otp = (fo >> 1) / 9;
        int ic = ((lane >> 4) * 8) + j, oc = (otp * 2 + oti) * 16 + (lane & 15);
        w3f[e] = f2h(w3[oc * 288 + ic * 9 + t]);
    }
    for (int s = gid; s < 608 * 192; s += gs) {
        int k = s / 192, n = s - k * 192;
        float v = 0.f;
        if (k < 584) {
            int f = (k < 576) ? ((k & 63) * 9 + (k >> 6)) : k;
            v = (n < 128) ? ptw1[f * 128 + n] : cfw1[f * 64 + (n - 128)];
        }
        int kk = k >> 5, hi = (k & 31) >> 3, j = k & 7, nt = n >> 4;
        int e = (((kk * 12 + nt) << 6) | (hi << 4) | (n & 15)) << 3 | j;
        w1hd[e] = f2h(v);
    }
    for (int s = gid; s < 8192; s += gs) {
        int k = s >> 6, n = s & 63;
        float v = ptw2[k * 64 + n];
        int kk = k >> 5, hi = (k & 31) >> 3, j = k & 7, nt = n >> 4;
        int e = ((((kk << 2) | nt) << 6) | (hi << 4) | (n & 15)) << 3 | j;
        w2hd[e] = f2h(v);
    }
    for (int e = gid; e < 2048; e += gs) {
        int j = e & 7, lane = (e >> 3) & 63, kk = e >> 9;
        int k = kk * 32 + ((lane >> 4) * 8) + j, n = lane & 15;
        float v = 0.f;
        if (k < 64) { if (n < 2) v = ptw3[k * 2 + n]; }
        else        { if (n == 2) v = cfw2[k - 64]; }
        w3hd[e] = f2h(v);
    }
}

// ---------------------------------------------------------------------------
// k_fused: convs + heads. Round-11 change: conv2 = read-once register rows,
// one oc-tile per wave (1 ds_read : 7 MFMA instead of 1:2). Rest = round 10.
// ---------------------------------------------------------------------------
#define BDS4 260
#define BDH4 (16 * BDS4)
#define A1S 584
#define A2S 296
#define FTS 616
#define HSH 200
#define RA_OFF 19712
#define O_OFF 26112
#define LDSTOT 26368

__global__ __launch_bounds__(256, 3) void k_fused(
    const float* __restrict__ board,
    const float* __restrict__ b1, const float* __restrict__ b2,
    const float* __restrict__ b3, const float* __restrict__ qp,
    const unsigned short* __restrict__ w1f,
    const unsigned short* __restrict__ w2f,
    const unsigned short* __restrict__ w3f,
    const unsigned short* __restrict__ w1hd,
    const unsigned short* __restrict__ w2hd,
    const unsigned short* __restrict__ w3hd,
    const float* __restrict__ ptb1, const float* __restrict__ ptb2,
    const float* __restrict__ ptb3, const float* __restrict__ cfb1,
    const float* __restrict__ cfb2,
    float* __restrict__ out)
{
    __shared__ __align__(16) unsigned short LDSH[LDSTOT];
    const int tid = threadIdx.x, wid = tid >> 6, lane = tid & 63;
    const int g = wid >> 1, w2 = wid & 1;
    const int col = lane & 15, q = lane >> 4;
    const long long gg0 = (long long)blockIdx.x * 32;
    const f32x4 ZERO4 = {0.f, 0.f, 0.f, 0.f};

    unsigned short* A1 = LDSH + g * 9856;
    unsigned short* A2 = A1;                          // overlay (barriered)
    unsigned short* Hb = LDSH + RA_OFF;               // overlays BD (dead)
    float* O = (float*)(LDSH + O_OFF);

    // ---- 1. zero BD staging buffer ----
    for (int e = tid; e < BDH4 / 4; e += 256)
        ((unsigned long long*)(LDSH + RA_OFF))[e] = 0ULL;
    __syncthreads();

    // ---- 2. per-group: stage board (ch-pad-4) -> quantum + conv1 ----
    float qv[2];
    h8 w1r0 = ((const h8*)w1f)[lane];
    h8 w1r1 = ((const h8*)w1f)[64 + lane];
    float b1v = b1[col];
    #pragma unroll
    for (int gi = 0; gi < 2; gi++) {
        for (int e = tid; e < 16 * 108; e += 256) {
            int ss = e / 108, r2 = e % 108, ch = r2 / 36, p = r2 % 36;
            float v = board[(gg0 + gi * 16) * 108 + e];
            LDSH[RA_OFF + ss * BDS4 + ((p / 6 + 1) * 8 + (p % 6) + 1) * 4 + ch] =
                f2h(v);
        }
        __syncthreads();
        if (tid < 128) {
            int ss = tid >> 3, qq = tid & 7;
            int base = RA_OFF + ss * BDS4;
            int p8a = ((qq / 6 + 1) * 8 + (qq % 6) + 1) * 4;
            int e2 = (qq + 1) & 7;
            int p8b = ((e2 / 6 + 1) * 8 + (e2 % 6) + 1) * 4;
            float xq = h2f(LDSH[base + p8a]);
            float xn = h2f(LDSH[base + p8b]);
            float st = 0.f;
            for (int l = 0; l < 3; l++) {
                float a0 = qp[l * 24 + qq * 3], a1 = qp[l * 24 + qq * 3 + 1],
                      a2 = qp[l * 24 + qq * 3 + 2];
                st = sinf(a0 * xq) * cosf(a1 * xn) + tanhf(a2 * st);
            }
            qv[gi] = st;
        }
        {
            unsigned short* A1g = LDSH + gi * 9856;
            const int bs = RA_OFF + col * BDS4;
            const int rsel = q >> 1, wo = (q & 1) * 8;
            for (int p = wid * 9; p < wid * 9 + 9; p++) {
                int y = p / 6, x = p % 6;
                int ab1 = bs + ((y + rsel) * 8 + x) * 4 + wo;
                int ab2 = bs + ((y + 2) * 8 + x) * 4 + wo;
                union { h8 v; h4 h[2]; } a1v, a2v;
                a1v.h[0] = *(const h4*)&LDSH[ab1];
                a1v.h[1] = *(const h4*)&LDSH[ab1 + 4];
                a2v.h[0] = *(const h4*)&LDSH[ab2];
                a2v.h[1] = *(const h4*)&LDSH[ab2 + 4];
                f32x4 c = MFMA16(a1v.v, w1r0, ZERO4);
                c = MFMA16(a2v.v, w1r1, c);
                #pragma unroll
                for (int r = 0; r < 4; r++)
                    A1g[(q * 4 + r) * A1S + p * 16 + col] =
                        f2h(fmaxf(c[r] + b1v, 0.f));
            }
        }
        __syncthreads();
    }

    // ---- 3. conv2: read-once register rows; wave = oc-tile w2, all 36 pos ----
    f32x4 pooled2[9];
    #pragma unroll
    for (int pp = 0; pp < 9; pp++) pooled2[pp] = ZERO4;
    {
        h8 W2r[9];
        #pragma unroll
        for (int t = 0; t < 9; t++)
            W2r[t] = ((const h8*)w2f)[(t * 2 + w2) * 64 + lane];
        float b2v = b2[w2 * 16 + col];
        const int sA1 = col * A1S;
        const int kho = (q & 1) * 8;

        h8 R[3][6];
        #pragma unroll
        for (int x = 0; x < 6; x++) {
            R[0][x] = *(const h8*)&A1[sA1 + (0 * 6 + x) * 16 + kho];
            R[1][x] = *(const h8*)&A1[sA1 + (1 * 6 + x) * 16 + kho];
        }
        #pragma unroll
        for (int y = 0; y < 6; y++) {
            if (y >= 1 && y <= 4) {
                const int nr = y + 1, slot = nr % 3;
                #pragma unroll
                for (int x = 0; x < 6; x++)
                    R[slot][x] = *(const h8*)&A1[sA1 + (nr * 6 + x) * 16 + kho];
            }
            f32x4 acc[6];
            #pragma unroll
            for (int x = 0; x < 6; x++) acc[x] = ZERO4;
            #pragma unroll
            for (int dy = -1; dy <= 1; dy++) {
                const int ry = y + dy;
                if (ry < 0 || ry > 5) continue;
                const int slot = ry % 3;
                #pragma unroll
                for (int x = 0; x < 6; x++)
                    #pragma unroll
                    for (int dx = -1; dx <= 1; dx++) {
                        const int sx = x + dx;
                        if (sx < 0 || sx > 5) continue;
                        acc[x] = MFMA16(R[slot][sx],
                                        W2r[(dy + 1) * 3 + (dx + 1)], acc[x]);
                    }
            }
            const int pr = y >> 1;
            #pragma unroll
            for (int px = 0; px < 3; px++)
                #pragma unroll
                for (int xx = 0; xx < 2; xx++)
                    #pragma unroll
                    for (int r = 0; r < 4; r++)
                        pooled2[pr * 3 + px][r] =
                            fmaxf(pooled2[pr * 3 + px][r],
                                  acc[px * 2 + xx][r] + b2v);
        }
    }
    __syncthreads();   // all A1 reads (block-wide) done before A2 overlays
    #pragma unroll
    for (int pp = 0; pp < 9; pp++)
        #pragma unroll
        for (int r = 0; r < 4; r++)
            A2[(q * 4 + r) * A2S + pp * 32 + w2 * 16 + col] =
                f2h(pooled2[pp][r]);
    __syncthreads();

    // ---- 4. conv3 -> registers (otp = w2) ----
    f32x4 c3a[9], c3b[9];
    {
        const int otp = w2;
        const int sA2 = col * A2S;
        h8 W3r[18];
        #pragma unroll
        for (int f = 0; f < 18; f++)
            W3r[f] = ((const h8*)w3f)[(otp * 18 + f) * 64 + lane];
        #pragma unroll
        for (int p = 0; p < 9; p++) {
            const int y = p / 3, x = p % 3;
            f32x4 acc0 = ZERO4, acc1 = ZERO4;
            #pragma unroll
            for (int t = 0; t < 9; t++) {
                const int sy = y + t / 3 - 1, sx = x + t % 3 - 1;
                if (sy < 0 || sy >= 3 || sx < 0 || sx >= 3) continue;
                h8 a = *(const h8*)&A2[sA2 + (sy * 3 + sx) * 32 + q * 8];
                acc0 = MFMA16(a, W3r[t * 2 + 0], acc0);
                acc1 = MFMA16(a, W3r[t * 2 + 1], acc1);
            }
            c3a[p] = acc0; c3b[p] = acc1;
        }
    }
    __syncthreads();   // all A2 reads done before FT overlays region B

    // ---- 5. write FT [p][oc] + quantum + zero tail cols 584..615 ----
    {
        const int otp = w2;
        float b3v0 = b3[(otp * 2 + 0) * 16 + col];
        float b3v1 = b3[(otp * 2 + 1) * 16 + col];
        int oc0 = (otp * 2 + 0) * 16 + col, oc1 = (otp * 2 + 1) * 16 + col;
        #pragma unroll
        for (int p = 0; p < 9; p++)
            #pragma unroll
            for (int r = 0; r < 4; r++) {
                int row = g * 16 + q * 4 + r;
                LDSH[row * FTS + p * 64 + oc0] = f2h(fmaxf(c3a[p][r] + b3v0, 0.f));
                LDSH[row * FTS + p * 64 + oc1] = f2h(fmaxf(c3b[p][r] + b3v1, 0.f));
            }
        if (tid < 128) {
            int ss = tid >> 3, qq = tid & 7;
            LDSH[ss * FTS + 576 + qq] = f2h(qv[0]);
            LDSH[(ss + 16) * FTS + 576 + qq] = f2h(qv[1]);
        }
        for (int e = tid; e < 1024; e += 256)
            LDSH[(e >> 5) * FTS + 584 + (e & 31)] = 0;
    }
    __syncthreads();

    // ---- 6. heads L1: K=608 (19 kk), wave does nt-tiles wid*3..+2, both mt ----
    {
        f32x4 acc[2][3];
        #pragma unroll
        for (int mt = 0; mt < 2; mt++)
            #pragma unroll
            for (int nt = 0; nt < 3; nt++) acc[mt][nt] = ZERO4;
        const h8* wp1 = (const h8*)w1hd;
        const int ntb = wid * 3;
        for (int kk = 0; kk < 19; kk++) {
            h8 a0 = *(const h8*)&LDSH[col * FTS + kk * 32 + q * 8];
            h8 a1 = *(const h8*)&LDSH[(16 + col) * FTS + kk * 32 + q * 8];
            h8 b[3];
            #pragma unroll
            for (int nt = 0; nt < 3; nt++)
                b[nt] = wp1[(kk * 12 + ntb + nt) * 64 + lane];
            #pragma unroll
            for (int nt = 0; nt < 3; nt++) {
                acc[0][nt] = MFMA16(a0, b[nt], acc[0][nt]);
                acc[1][nt] = MFMA16(a1, b[nt], acc[1][nt]);
            }
        }
        #pragma unroll
        for (int nt = 0; nt < 3; nt++) {
            int ntg = ntb + nt;
            float bv = (ntg < 8) ? ptb1[ntg * 16 + col] : cfb1[(ntg - 8) * 16 + col];
            #pragma unroll
            for (int mt = 0; mt < 2; mt++)
                #pragma unroll
                for (int r = 0; r < 4; r++)
                    Hb[(mt * 16 + q * 4 + r) * HSH + ntg * 16 + col] =
                        f2h(fmaxf(acc[mt][nt][r] + bv, 0.f));
        }
    }
    __syncthreads();

    // ---- 7. heads L2: nt = wid, both mt ----
    {
        f32x4 acc2[2];
        acc2[0] = ZERO4; acc2[1] = ZERO4;
        const h8* wp2 = (const h8*)w2hd;
        const int nt2 = wid;
        #pragma unroll
        for (int kk = 0; kk < 4; kk++) {
            h8 a0 = *(const h8*)&Hb[col * HSH + kk * 32 + q * 8];
            h8 a1 = *(const h8*)&Hb[(16 + col) * HSH + kk * 32 + q * 8];
            h8 b = wp2[(kk * 4 + nt2) * 64 + lane];
            acc2[0] = MFMA16(a0, b, acc2[0]);
            acc2[1] = MFMA16(a1, b, acc2[1]);
        }
        __syncthreads();   // all L2 reads done before overwriting cols 0..63
        float bv2 = ptb2[nt2 * 16 + col];
        #pragma unroll
        for (int mt = 0; mt < 2; mt++)
            #pragma unroll
            for (int r = 0; r < 4; r++)
                Hb[(mt * 16 + q * 4 + r) * HSH + nt2 * 16 + col] =
                    f2h(fmaxf(acc2[mt][r] + bv2, 0.f));
    }
    __syncthreads();

    // ---- 8. heads L3 + epilogue: waves 0,1 handle mt = wid ----
    if (wid < 2) {
        const int mt = wid;
        f32x4 a3 = ZERO4;
        #pragma unroll
        for (int kk = 0; kk < 4; kk++) {
            int base = (kk < 2) ? kk * 32 : kk * 32 + 64;
            h8 a = *(const h8*)&Hb[(mt * 16 + col) * HSH + base + q * 8];
            h8 b = ((const h8*)w3hd)[kk * 64 + lane];
            a3 = MFMA16(a, b, a3);
        }
        if (col < 3) {
            float bv = (col < 2) ? ptb3[col] : cfb2[0];
            #pragma unroll
            for (int r = 0; r < 4; r++)
                O[(mt * 16 + q * 4 + r) * 4 + col] = a3[r] + bv;
        }
        if (lane < 16) {
            int s = mt * 16 + lane;
            float l0 = O[s * 4 + 0], l1 = O[s * 4 + 1], l2 = O[s * 4 + 2];
            float m = fmaxf(l0, l1);
            float e0 = expf(l0 - m), e1 = expf(l1 - m);
            float inv = 1.f / (e0 + e1);
            float* op = out + (gg0 + s) * 3;
            op[0] = e0 * inv;
            op[1] = e1 * inv;
            op[2] = 1.f / (1.f + expf(-l2));
        }
    }
}

extern "C" void kernel_launch(void* const* d_in, const int* in_sizes, int n_in,
                              void* d_out, int out_size, void* d_ws, size_t ws_size,
                              hipStream_t stream) {
    const float* board = (const float*)d_in[0];
    const float* c1w  = (const float*)d_in[2];
    const float* c1b  = (const float*)d_in[3];
    const float* c2w  = (const float*)d_in[4];
    const float* c2b  = (const float*)d_in[5];
    const float* c3w  = (const float*)d_in[6];
    const float* c3b  = (const float*)d_in[7];
    const float* qp   = (const float*)d_in[8];
    const float* ptw1 = (const float*)d_in[9];
    const float* ptb1 = (const float*)d_in[10];
    const float* ptw2 = (const float*)d_in[11];
    const float* ptb2 = (const float*)d_in[12];
    const float* ptw3 = (const float*)d_in[13];
    const float* ptb3 = (const float*)d_in[14];
    const float* cfw1 = (const float*)d_in[15];
    const float* cfb1 = (const float*)d_in[16];
    const float* cfw2 = (const float*)d_in[17];
    const float* cfb2 = (const float*)d_in[18];
    float* out = (float*)d_out;

    int Btot = in_sizes[0] / 108;          // 65536

    unsigned short* w1f   = (unsigned short*)d_ws;
    unsigned short* w2f   = (unsigned short*)((char*)d_ws + 2048);
    unsigned short* w3f   = (unsigned short*)((char*)d_ws + 20480);
    unsigned short* w1hd  = (unsigned short*)((char*)d_ws + 57344);
    unsigned short* w2hd  = (unsigned short*)((char*)d_ws + 290816);
    unsigned short* w3hd  = (unsigned short*)((char*)d_ws + 307200);

    hipLaunchKernelGGL(k_prep, dim3(256), dim3(256), 0, stream,
                       c1w, c2w, c3w, ptw1, cfw1, ptw2, ptw3, cfw2,
                       w1f, w2f, w3f, w1hd, w2hd, w3hd);
    hipLaunchKernelGGL(k_fused, dim3(Btot / 32), dim3(256), 0, stream,
                       board, c1b, c2b, c3b, qp, w1f, w2f, w3f,
                       w1hd, w2hd, w3hd, ptb1, ptb2, ptb3, cfb1, cfb2, out);
}